// Round 8
// baseline (150.189 us; speedup 1.0000x reference)
//
#include <hip/hip_runtime.h>
#include <hip/hip_bf16.h>

#define B_ 16
#define T_ 1024
#define MEL_ 80
#define C_ 512
#define NL_ 6
#define NS_ 32
#define KSTR 32      // tap storage stride; builder fills 32, MFMA path uses ALL 32
#define HBSTR 1096   // per-wave LDS h-buffer stride (halves): 32 pad + 1024 + 40 tail

typedef float v2f __attribute__((ext_vector_type(2)));
typedef _Float16 f16x8 __attribute__((ext_vector_type(8)));
typedef float f32x4 __attribute__((ext_vector_type(4)));

// ---------------------------------------------------------------- wave reduce
__device__ __forceinline__ float wred(float v) {
#pragma unroll
    for (int m = 32; m >= 1; m >>= 1) v += __shfl_xor(v, m, 64);
    return v;
}

__device__ __forceinline__ unsigned int pkh(float a, float b) {
    typedef __fp16 h2 __attribute__((ext_vector_type(2)));
    h2 r = __builtin_amdgcn_cvt_pkrtz(a, b);   // builtin returns __fp16x2
    return __builtin_bit_cast(unsigned int, r);
}
__device__ __forceinline__ float h2f(unsigned short u) {
    return (float)__builtin_bit_cast(_Float16, u);
}

// ---------------------------------------------------------------- input proj (+ fused tap build)
// Main: h0T16[b][c][t] (transposed, f16) for conv's coalesced per-wave entry.
// f16 pack here is the SAME cvt_pkrtz the conv entry used to apply -> bit-identical.
// Tail: blocks with by<6 also build layer-by's taps.
// Kt[(l*C + c)*KSTR + tau]; Kt[..][0] absorbs D.
__global__ __launch_bounds__(256) void in_proj(const float* __restrict__ mel,
                                               const float* __restrict__ w_in,
                                               const float* __restrict__ b_in,
                                               const float* __restrict__ freq,
                                               const float* __restrict__ logA,
                                               const float* __restrict__ Cp,
                                               const float* __restrict__ Dp,
                                               unsigned short* __restrict__ h0T,
                                               float* __restrict__ Kt) {
    __shared__ float lds[C_ * 20];      // 40,960 B
    const int b = blockIdx.y;
    const int t0 = blockIdx.x * 16;
    const int tid = threadIdx.x;
    const float* melb = mel + ((size_t)b * T_ + t0) * MEL_;

    v2f acc[16];
#pragma unroll
    for (int t = 0; t < 16; ++t) acc[t] = (v2f){0.f, 0.f};
#pragma unroll 4
    for (int k = 0; k < MEL_; ++k) {
        v2f w01 = {w_in[(size_t)k * C_ + tid], w_in[(size_t)k * C_ + tid + 256]};
#pragma unroll
        for (int t = 0; t < 16; ++t) {
            float mv = melb[t * MEL_ + k];       // wave-uniform s_load
            acc[t] = __builtin_elementwise_fma((v2f){mv, mv}, w01, acc[t]);
        }
    }
    float bias0 = b_in[tid], bias1 = b_in[tid + 256];
#pragma unroll
    for (int t = 0; t < 16; ++t) {
        int tt = t0 + t;
        int fr = tt < 513 ? tt : 512;
        lds[tid * 20 + t] = acc[t][0] + bias0 + freq[(size_t)fr * C_ + tid];
        lds[(tid + 256) * 20 + t] = acc[t][1] + bias1 + freq[(size_t)fr * C_ + tid + 256];
    }
    __syncthreads();
    const int tq = tid & 3;
#pragma unroll
    for (int rep = 0; rep < 8; ++rep) {
        int c = 64 * rep + (tid >> 2);
        float4 v = *(const float4*)(&lds[c * 20 + 4 * tq]);
        uint2 pw;
        pw.x = pkh(v.x, v.y);
        pw.y = pkh(v.z, v.w);
        *(uint2*)(h0T + ((size_t)b * C_ + c) * T_ + t0 + 4 * tq) = pw;
    }

    // fused tap build: 6*64 blocks cover (l=by, idx = bx*256+tid -> c,tau)
    if (b < NL_) {
        int idx = blockIdx.x * 256 + tid;          // 0..16383
        int tau = idx & (KSTR - 1);
        int c = idx >> 5;
        const float* la = logA + ((size_t)b * C_ + c) * NS_;
        const float* cp = Cp + ((size_t)b * C_ + c) * NS_;
        float s = 0.f;
        float t = (float)tau;
#pragma unroll 8
        for (int n = 0; n < NS_; ++n)
            s += cp[n] * expf(-expf(la[n]) * t);
        if (tau == 0) s += Dp[b * C_ + c];
        Kt[((size_t)b * C_ + c) * KSTR + tau] = s;
    }
}

// ---------------------------------------------------------------- tap fragments
// Build per-(l,c) MFMA A-operand fragments (f16) from Kt:
//   A_hi[m][k] = K[32+m-k], A_lo[m][k] = K[m-k], zero out of [0,32).
// Fragment layout (v_mfma_f32_16x16x32_f16 A): lane holds A[lane&15][8*(lane>>4)+e].
// One wave per (l,c); stores 8 halves (16B) per lane per matrix.
__global__ __launch_bounds__(256) void tap_frags(const float* __restrict__ Kt,
                                                 unsigned short* __restrict__ AH,
                                                 unsigned short* __restrict__ AL) {
    const int gid = blockIdx.x * 4 + (threadIdx.x >> 6);   // l*512 + c
    const int lane = threadIdx.x & 63;
    const float* kp = Kt + (size_t)gid * KSTR;
    float kv = kp[lane & 31];                // lanes 0..31 hold taps 0..31
    const int m = lane & 15, hh = lane >> 4;
    f16x8 vh, vl;
#pragma unroll
    for (int e = 0; e < 8; ++e) {
        int th = 32 + m - 8 * hh - e;
        int tl = m - 8 * hh - e;
        float a = __shfl(kv, th & 31, 64);
        float bq = __shfl(kv, tl & 31, 64);
        vh[e] = (th >= 0 && th < 32) ? (_Float16)a : (_Float16)0.f;
        vl[e] = (tl >= 0 && tl < 32) ? (_Float16)bq : (_Float16)0.f;
    }
    *(f16x8*)(AH + (size_t)gid * 512 + lane * 8) = vh;
    *(f16x8*)(AL + (size_t)gid * 512 + lane * 8) = vl;
}

// ---------------------------------------------------------------- fused 6-layer S4D stack (MFMA)
// ONE CHANNEL PER WAVE; h lives in a wave-private LDS f16 buffer (no barriers
// in the layer loop). Per layer: 2 global dwordx4 (A frags), 8 ds_read_b128
// (B windows), 8 mfma_f32_16x16x32_f16, f32 gelu, 4 ds_write_b64.
// Toeplitz split: D[m][n] = sum_k Ahi[m][k] h[256q+16n-32+k]
//                          + sum_k Alo[m][k] h[256q+16n+k]  = y[256q+16n+m].
// Entry/exit are f16 end-to-end (R7: inter-kernel f32 traffic was the
// remaining cost; values are f16-rounded anyway -> bit-identical).
__global__ __launch_bounds__(512) void conv_stack(const unsigned short* __restrict__ h0T,
                                                  unsigned short* __restrict__ hfin,
                                                  const unsigned short* __restrict__ AH,
                                                  const unsigned short* __restrict__ AL,
                                                  float* __restrict__ hm) {
    __shared__ unsigned short HB[8 * HBSTR];   // 17,536 B
    const int b = blockIdx.y;
    const int gx = blockIdx.x;                       // 64 groups
    const int c0 = 8 * (((gx & 7) << 3) | (gx >> 3)); // XCD i -> channels 64i..64i+63
    const int tid = threadIdx.x;
    const int lane = tid & 63;
    const int wv = tid >> 6;
    const int c = __builtin_amdgcn_readfirstlane(c0 + wv);   // wave-uniform channel
    unsigned short* hb = &HB[wv * HBSTR];

    // zero pads: [0,32) front (h[t<0]=0), [1056,1096) tail (avoid NaN*0 in MFMA)
    if (lane < 32) hb[lane] = 0;
    if (lane < 40) hb[1056 + lane] = 0;

    {   // entry: lane L copies t = 16L..16L+15 (f16, 32 B) straight into hb
        const unsigned short* srcT = h0T + ((size_t)b * C_ + c) * T_ + 16 * lane;
        uint4 p0 = *(const uint4*)(srcT);
        uint4 p1 = *(const uint4*)(srcT + 8);
        *(uint4*)(&hb[32 + 16 * lane]) = p0;
        *(uint4*)(&hb[32 + 16 * lane + 8]) = p1;
    }

    const int n = lane & 15, hh = lane >> 4;
    const int boff = 16 * n + 8 * hh;                // q-base added in loop
    const int woff = 32 + 16 * n + 4 * hh;           // layer output write base

    f16x8 Ah = *(const f16x8*)(AH + (size_t)c * 512 + lane * 8);   // l=0
    f16x8 Al = *(const f16x8*)(AL + (size_t)c * 512 + lane * 8);

    float hsum = 0.f;
    for (int l = 0; l < NL_; ++l) {
        const int ln = (l + 1 < NL_) ? l + 1 : 0;    // dummy prefetch on last
        f16x8 nAh = *(const f16x8*)(AH + ((size_t)ln * C_ + c) * 512 + lane * 8);
        f16x8 nAl = *(const f16x8*)(AL + ((size_t)ln * C_ + c) * 512 + lane * 8);

        f32x4 d[4];
#pragma unroll
        for (int q = 0; q < 4; ++q) {
            const unsigned short* base = hb + 256 * q + boff;
            f16x8 Bh = *(const f16x8*)(base);          // h[256q+16n-32+k]
            f16x8 Bl = *(const f16x8*)(base + 32);     // h[256q+16n+k]
            f32x4 z = {0.f, 0.f, 0.f, 0.f};
            d[q] = __builtin_amdgcn_mfma_f32_16x16x32_f16(Ah, Bh, z, 0, 0, 0);
            d[q] = __builtin_amdgcn_mfma_f32_16x16x32_f16(Al, Bl, d[q], 0, 0, 0);
        }
        // gelu (f32) + pack back to f16 h-buffer
#pragma unroll
        for (int q = 0; q < 4; ++q) {
            float g[4];
#pragma unroll
            for (int r = 0; r < 4; ++r) {
                float y = d[q][r];
                float u2 = y * (y * y * 0.07135481627f + 1.59576912161f);
                float rr = __builtin_amdgcn_rcpf(__expf(u2) + 1.f);
                g[r] = y - y * rr;
            }
            if (l == NL_ - 1) hsum += g[0] + g[1] + g[2] + g[3];
            uint2 pw;
            pw.x = pkh(g[0], g[1]);
            pw.y = pkh(g[2], g[3]);
            *(uint2*)(&hb[woff + 256 * q]) = pw;       // t = 256q+16n+4hh+r
        }
        Ah = nAh; Al = nAl;
    }

    // time mean per channel
    {
        float s = wred(hsum);
        if (lane == 0) hm[(size_t)b * C_ + c] = s * (1.f / T_);
    }

    // exit: cross-wave LDS transpose -> hfin16[b][t][C] (raw u16 copy)
    __syncthreads();
    {
        unsigned short* dst = hfin + (size_t)b * T_ * C_ + c0;
#pragma unroll
        for (int it = 0; it < 4; ++it) {
            int idx = it * 512 + tid;                 // 0..2047
            int t = idx >> 1, u = idx & 1;
            unsigned int w0 = (unsigned int)HB[(4 * u + 0) * HBSTR + 32 + t] |
                              ((unsigned int)HB[(4 * u + 1) * HBSTR + 32 + t] << 16);
            unsigned int w1 = (unsigned int)HB[(4 * u + 2) * HBSTR + 32 + t] |
                              ((unsigned int)HB[(4 * u + 3) * HBSTR + 32 + t] << 16);
            uint2 pw = {w0, w1};
            *(uint2*)(dst + (size_t)t * C_ + 4 * u) = pw;
        }
    }
}

// ---------------------------------------------------------------- per-row heads
// Row-major single-pass version: params hoisted into registers once per wave;
// each wave processes 4 rows. Input h is f16 (widened on load -- exact).
__global__ __launch_bounds__(256) void heads_rows(const unsigned short* __restrict__ h,
                                                  const float* __restrict__ ln_g,
                                                  const float* __restrict__ ln_b,
                                                  const float* __restrict__ w5,
                                                  const float* __restrict__ b5,
                                                  float* __restrict__ out) {
    int wv = threadIdx.x >> 6, lane = threadIdx.x & 63;
    int r0 = blockIdx.x * 16 + wv * 4;
    float g[3][8], bb[3][8], ww[3][8];
#pragma unroll
    for (int o = 0; o < 3; ++o) {
        const float* gp = ln_g + o * C_ + lane * 8;
        const float* bp = ln_b + o * C_ + lane * 8;
        const float* wp = w5 + o * C_ + lane * 8;
        float4 a, bq;
        a = *(const float4*)(gp); bq = *(const float4*)(gp + 4);
        g[o][0]=a.x; g[o][1]=a.y; g[o][2]=a.z; g[o][3]=a.w;
        g[o][4]=bq.x; g[o][5]=bq.y; g[o][6]=bq.z; g[o][7]=bq.w;
        a = *(const float4*)(bp); bq = *(const float4*)(bp + 4);
        bb[o][0]=a.x; bb[o][1]=a.y; bb[o][2]=a.z; bb[o][3]=a.w;
        bb[o][4]=bq.x; bb[o][5]=bq.y; bb[o][6]=bq.z; bb[o][7]=bq.w;
        a = *(const float4*)(wp); bq = *(const float4*)(wp + 4);
        ww[o][0]=a.x; ww[o][1]=a.y; ww[o][2]=a.z; ww[o][3]=a.w;
        ww[o][4]=bq.x; ww[o][5]=bq.y; ww[o][6]=bq.z; ww[o][7]=bq.w;
    }
    float b5r[3] = {b5[0], b5[1], b5[2]};
#pragma unroll
    for (int rr = 0; rr < 4; ++rr) {
        const int r = r0 + rr;
        const unsigned short* row = h + (size_t)r * C_ + lane * 8;
        float x[8];
        {
            uint4 q = *(const uint4*)(row);
            x[0] = h2f((unsigned short)(q.x & 0xffff));
            x[1] = h2f((unsigned short)(q.x >> 16));
            x[2] = h2f((unsigned short)(q.y & 0xffff));
            x[3] = h2f((unsigned short)(q.y >> 16));
            x[4] = h2f((unsigned short)(q.z & 0xffff));
            x[5] = h2f((unsigned short)(q.z >> 16));
            x[6] = h2f((unsigned short)(q.w & 0xffff));
            x[7] = h2f((unsigned short)(q.w >> 16));
        }
        float s = 0.f;
#pragma unroll
        for (int i = 0; i < 8; ++i) s += x[i];
        float mu = wred(s) * (1.f / C_);
        float v = 0.f;
#pragma unroll
        for (int i = 0; i < 8; ++i) { float d = x[i] - mu; v += d * d; }
        float rstd = rsqrtf(wred(v) * (1.f / C_) + 1e-5f);
#pragma unroll
        for (int o = 0; o < 3; ++o) {
            float acc = 0.f;
#pragma unroll
            for (int i = 0; i < 8; ++i) {
                float xn = (x[i] - mu) * rstd * g[o][i] + bb[o][i];
                acc += xn * ww[o][i];
            }
            acc = wred(acc);
            if (lane == 0) out[o * (B_ * T_) + r] = acc + b5r[o];
        }
    }
}

// ---------------------------------------------------------------- utterance heads
__global__ __launch_bounds__(64) void heads_utt(const float* __restrict__ hm,
                                                const float* __restrict__ ln_g,
                                                const float* __restrict__ ln_b,
                                                const float* __restrict__ w5,
                                                const float* __restrict__ b5,
                                                const float* __restrict__ wm,
                                                const float* __restrict__ bm,
                                                float* __restrict__ out) {
    int b = blockIdx.x;
    int lane = threadIdx.x;
    const float* row = hm + (size_t)b * C_;
    float x[8];
#pragma unroll
    for (int i = 0; i < 8; ++i) x[i] = row[lane + 64 * i];
    float s = 0.f;
#pragma unroll
    for (int i = 0; i < 8; ++i) s += x[i];
    float mu = wred(s) * (1.f / C_);
    float v = 0.f;
#pragma unroll
    for (int i = 0; i < 8; ++i) { float d = x[i] - mu; v += d * d; }
    float rstd = rsqrtf(wred(v) * (1.f / C_) + 1e-5f);

    const int OUT_SR = 3 * B_ * T_;              // 49152
    const int OUT_PD = OUT_SR + B_;              // 49168
    const int OUT_MF = OUT_PD + B_;              // 49184
#pragma unroll
    for (int o = 3; o <= 4; ++o) {
        float acc = 0.f;
#pragma unroll
        for (int i = 0; i < 8; ++i) {
            int cc = lane + 64 * i;
            float xn = (x[i] - mu) * rstd * ln_g[o * C_ + cc] + ln_b[o * C_ + cc];
            acc += xn * w5[o * C_ + cc];
        }
        acc = wred(acc);
        if (lane == 0) out[(o == 3 ? OUT_SR : OUT_PD) + b] = acc + b5[o];
    }
    float mf[13];
#pragma unroll
    for (int j = 0; j < 13; ++j) mf[j] = 0.f;
#pragma unroll
    for (int i = 0; i < 8; ++i) {
        int cc = lane + 64 * i;
        float xn = (x[i] - mu) * rstd * ln_g[5 * C_ + cc] + ln_b[5 * C_ + cc];
#pragma unroll
        for (int j = 0; j < 13; ++j) mf[j] += xn * wm[cc * 13 + j];
    }
#pragma unroll
    for (int j = 0; j < 13; ++j) {
        float m = wred(mf[j]);
        if (lane == 0) out[OUT_MF + b * 13 + j] = m + bm[j];
    }
}

// ---------------------------------------------------------------- launch
extern "C" void kernel_launch(void* const* d_in, const int* in_sizes, int n_in,
                              void* d_out, int out_size, void* d_ws, size_t ws_size,
                              hipStream_t stream) {
    const float* mel   = (const float*)d_in[0];
    const float* w_in  = (const float*)d_in[1];
    const float* b_in  = (const float*)d_in[2];
    const float* freq  = (const float*)d_in[3];
    const float* logA  = (const float*)d_in[4];
    const float* s4C   = (const float*)d_in[5];
    const float* s4D   = (const float*)d_in[6];
    const float* ln_g  = (const float*)d_in[7];
    const float* ln_b  = (const float*)d_in[8];
    const float* w5    = (const float*)d_in[9];
    const float* b5    = (const float*)d_in[10];
    const float* wm    = (const float*)d_in[11];
    const float* bm    = (const float*)d_in[12];
    float* out = (float*)d_out;

    char* ws = (char*)d_ws;
    const size_t H16 = (size_t)B_ * T_ * C_ * sizeof(unsigned short);  // 16.78 MB
    unsigned short* hA16 = (unsigned short*)ws;                        // h0T16 [b][c][t]
    unsigned short* hB16 = (unsigned short*)(ws + H16);                // hfin16 [b][t][C]
    float* Kt = (float*)(ws + 2 * H16);                                // 6*512*32 f32
    char*  p  = ws + 2 * H16 + (size_t)NL_ * C_ * KSTR * sizeof(float);
    float* hm = (float*)p;                                             // 16*512 f32
    unsigned short* AH = (unsigned short*)(p + (size_t)B_ * C_ * sizeof(float));
    unsigned short* AL = AH + (size_t)NL_ * C_ * 512;                  // 3.1 MB each

    in_proj<<<dim3(T_ / 16, B_), 256, 0, stream>>>(mel, w_in, b_in, freq,
                                                   logA, s4C, s4D, hA16, Kt);
    tap_frags<<<(NL_ * C_) / 4, 256, 0, stream>>>(Kt, AH, AL);
    conv_stack<<<dim3(C_ / 8, B_), 512, 0, stream>>>(hA16, hB16, AH, AL, hm);
    heads_rows<<<(B_ * T_) / 16, 256, 0, stream>>>(hB16, ln_g, ln_b, w5, b5, out);
    heads_utt<<<B_, 64, 0, stream>>>(hm, ln_g, ln_b, w5, b5, wm, bm, out);
}